// Round 5
// baseline (878.257 us; speedup 1.0000x reference)
//
#include <hip/hip_runtime.h>
#include <hip/hip_bf16.h>
#include <math.h>

#define B_SZ 8
#define L_SZ 2048
#define D_SZ 1024
#define H_SZ 16
#define DK_SZ 64
#define TOPK 7
#define M_SZ (B_SZ * L_SZ)   // 16384

typedef __attribute__((ext_vector_type(8))) short short8;
typedef __attribute__((ext_vector_type(4))) float float4v;
typedef unsigned short ushort_t;
typedef unsigned int uint_t;

__device__ __forceinline__ ushort_t f2bf(float x) {
    uint_t u = __float_as_uint(x);
    uint_t r = (u + 0x7fffu + ((u >> 16) & 1u)) >> 16;   // RNE
    return (ushort_t)r;
}

// Truncation split: x ~= hi + lo with |err| <= 2^-16 |x|.
__device__ __forceinline__ void split8(float4 x, float4 y, short8& hi, short8& lo) {
    float f[8] = {x.x, x.y, x.z, x.w, y.x, y.y, y.z, y.w};
#pragma unroll
    for (int i = 0; i < 8; ++i) {
        uint_t b = __float_as_uint(f[i]);
        hi[i] = (short)(b >> 16);
        float r = f[i] - __uint_as_float(b & 0xffff0000u);
        lo[i] = (short)(__float_as_uint(r) >> 16);
    }
}

// async global->LDS, 16B per lane. LDS dest must be wave-uniform base.
__device__ __forceinline__ void gl_lds16(const ushort_t* g, ushort_t* l) {
    __builtin_amdgcn_global_load_lds(
        (const __attribute__((address_space(1))) unsigned int*)g,
        (__attribute__((address_space(3))) unsigned int*)l, 16, 0, 0);
}

// ---------------------------------------------------------------------------
// K0: zero the corr accumulator (re-poisoned to 0xAA before every call)
// ---------------------------------------------------------------------------
__global__ __launch_bounds__(256)
void zero_f32(float* __restrict__ p, int n4) {
    int i = blockIdx.x * 256 + threadIdx.x;
    if (i < n4) ((float4*)p)[i] = make_float4(0.f, 0.f, 0.f, 0.f);
}

// ---------------------------------------------------------------------------
// K0b: split a fp32 array into hi/lo bf16 arrays (for the W matrices).
// ---------------------------------------------------------------------------
__global__ __launch_bounds__(256)
void split_fp32(const float* __restrict__ X, ushort_t* __restrict__ hi,
                ushort_t* __restrict__ lo, int n8) {
    int i = blockIdx.x * 256 + threadIdx.x;
    if (i >= n8) return;
    float4 a = ((const float4*)X)[2 * i];
    float4 b = ((const float4*)X)[2 * i + 1];
    short8 h, l;
    split8(a, b, h, l);
    *(short8*)(hi + (size_t)i * 8) = h;
    *(short8*)(lo + (size_t)i * 8) = l;
}

// ---------------------------------------------------------------------------
// K1 v3: Y = X @ W^T + bias via split-bf16 MFMA (hh + hl + lh), ring-pipelined.
//   R4 diagnosis: __syncthreads 2-phase forced vmcnt(0) drain per K-step ->
//   barrier/latency bound (MfmaUtil 33%, nothing saturated). This version
//   ports corr_mfma's proven counted-vmcnt ring (T3/T4):
//   - B tiles (pre-split Whi/Wlo) staged by global_load_lds into a 3-deep
//     LDS ring, prefetch distance 2; vmcnt(4) at the barrier (NEVER 0) so
//     the next stage's 4 DMA loads stay in flight across it.
//   - A tiles: fp32 loads (t+1) -> regs -> split8 -> ds_write into a 2-deep
//     ring after the MFMA block; lgkmcnt(0) before the raw s_barrier.
//   - Ring safety: overwrite of a slot is issued only after the barrier
//     that follows its last reads (R >= P+1 on both rings).
//   - LDS layout [hl][row][4 granules][8] with granule-XOR swizzle
//     c = g ^ ((row ^ row>>2) & 3) (involution, applied on write-side c and
//     read-side c) -> all ds ops <=2-way per quarter-wave.
//   - T1 XCD swizzle kept (FETCH at compulsory). T5 setprio around MFMAs.
//   LDS 80KB -> 2 blocks/CU; the per-wave split stall is covered by the
//   sibling block.
// ---------------------------------------------------------------------------
template <bool BF16OUT>
__global__ __launch_bounds__(256)
void gemm_split_mfma(const float* __restrict__ X, const ushort_t* __restrict__ Whi,
                     const ushort_t* __restrict__ Wlo, const float* __restrict__ bias,
                     void* __restrict__ Yv, int M, int N, int K) {
    __shared__ __align__(16) ushort_t Alds[2][2][128][4][8];   // 32 KB
    __shared__ __align__(16) ushort_t Blds[3][2][128][4][8];   // 48 KB

    const int tid = threadIdx.x;
    const int lane = tid & 63;
    const int wave = tid >> 6;
    const int wm = wave >> 1, wn = wave & 1;

    // T1 XCD-chunked swizzle (bijective, nwg % 8 == 0)
    const int flat = blockIdx.y * gridDim.x + blockIdx.x;
    const int cpx  = (gridDim.x * gridDim.y) >> 3;
    const int swzb = (flat & 7) * cpx + (flat >> 3);
    const int bx   = swzb % gridDim.x;
    const int by   = swzb / gridDim.x;
    const size_t m0 = (size_t)by * 128;
    const size_t n0 = (size_t)bx * 128;

    const int NT = K >> 5;               // K-tiles of 32

    // ---- A staging mapping: thread -> row (tid>>1), k-halftile (tid&1)*16
    const int arow = tid >> 1;
    const int g0   = (tid & 1) * 2;
    const int sA   = (arow ^ (arow >> 2)) & 3;
    const int c00  = g0 ^ sA, c01 = (g0 + 1) ^ sA;
    const float* Xp = X + (m0 + arow) * K + (tid & 1) * 16;
    ushort_t* Awr = &Alds[0][0][arow][0][0];   // + slot*8192 + hl*4096 + c*8

    // ---- B staging mapping: i=0..3, linear granule GB = wave*256 + i*64 + lane
    const ushort_t* bptr[4];
    int blbase[4];
#pragma unroll
    for (int i = 0; i < 4; ++i) {
        const int GB  = wave * 256 + i * 64 + lane;
        const int arr = GB >> 9;                   // 0: hi, 1: lo
        const int row = (GB >> 2) & 127;
        const int c   = GB & 3;
        const int gs  = c ^ ((row ^ (row >> 2)) & 3);   // pre-swizzled source granule
        bptr[i]   = (arr ? Wlo : Whi) + (n0 + row) * K + gs * 8;
        blbase[i] = wave * 2048 + i * 512;         // lane-uniform LDS base (shorts)
    }

    // ---- fragment read offsets (shorts, within one [hl] plane)
    const int fr = lane & 15;
    const int fg = lane >> 4;
    int offA[4], offB[4];
#pragma unroll
    for (int i = 0; i < 4; ++i) {
        const int ra = wm * 64 + i * 16 + fr;
        offA[i] = ra * 32 + (fg ^ ((ra ^ (ra >> 2)) & 3)) * 8;
        const int rb = wn * 64 + i * 16 + fr;
        offB[i] = rb * 32 + (fg ^ ((rb ^ (rb >> 2)) & 3)) * 8;
    }

    float4v acc[4][4];
#pragma unroll
    for (int i = 0; i < 4; ++i)
#pragma unroll
        for (int j = 0; j < 4; ++j) acc[i][j] = (float4v){0.f, 0.f, 0.f, 0.f};

    // ---- prologue: A(0) fp32 -> regs; stage B(0),B(1); split+write A(0)
    float4 ax0 = *(const float4*)(Xp + 0);
    float4 ax1 = *(const float4*)(Xp + 4);
    float4 ax2 = *(const float4*)(Xp + 8);
    float4 ax3 = *(const float4*)(Xp + 12);
#pragma unroll
    for (int i = 0; i < 4; ++i) gl_lds16(bptr[i],      &Blds[0][0][0][0][0] + blbase[i]);
#pragma unroll
    for (int i = 0; i < 4; ++i) gl_lds16(bptr[i] + 32, &Blds[1][0][0][0][0] + blbase[i]);
    {
        short8 h, l;
        split8(ax0, ax1, h, l);
        *(short8*)(Awr + c00 * 8) = h;  *(short8*)(Awr + 4096 + c00 * 8) = l;
        split8(ax2, ax3, h, l);
        *(short8*)(Awr + c01 * 8) = h;  *(short8*)(Awr + 4096 + c01 * 8) = l;
    }
    asm volatile("s_waitcnt lgkmcnt(0)" ::: "memory");
    asm volatile("s_waitcnt vmcnt(4)" ::: "memory");   // B(0) landed; B(1) in flight
    __builtin_amdgcn_s_barrier();
    asm volatile("" ::: "memory");

    int sa = 0;    // A ring slot holding tile t
    int sb = 0;    // B ring slot holding tile t
    for (int t = 0; t < NT; ++t) {
        const int tn1 = (t + 1) & (NT - 1);
        const int tn2 = (t + 2) & (NT - 1);
        const int san = sa ^ 1;
        const int sbn2 = (sb + 2 >= 3) ? sb - 1 : sb + 2;

        // (a) A(t+1) fp32 -> regs (wrap at end: harmless restage)
        const int ka = tn1 * 32;
        ax0 = *(const float4*)(Xp + ka + 0);
        ax1 = *(const float4*)(Xp + ka + 4);
        ax2 = *(const float4*)(Xp + ka + 8);
        ax3 = *(const float4*)(Xp + ka + 12);

        // (b) stage B(t+2) into ring slot sbn2 (issued after the barrier ->
        //     its last readers (step t-1) are already past their reads)
        {
            const int kt = tn2 * 32;
            ushort_t* sbase = &Blds[sbn2][0][0][0][0];
#pragma unroll
            for (int i = 0; i < 4; ++i) gl_lds16(bptr[i] + kt, sbase + blbase[i]);
        }

        // (c) fragment reads for tile t
        const ushort_t* Ab = &Alds[sa][0][0][0][0];
        const ushort_t* Bb = &Blds[sb][0][0][0][0];
        short8 afh[4], afl[4], bfh[4], bfl[4];
#pragma unroll
        for (int i = 0; i < 4; ++i) {
            afh[i] = *(const short8*)(Ab + offA[i]);
            afl[i] = *(const short8*)(Ab + 4096 + offA[i]);
            bfh[i] = *(const short8*)(Bb + offB[i]);
            bfl[i] = *(const short8*)(Bb + 4096 + offB[i]);
        }

        // (d) 48 MFMAs
        __builtin_amdgcn_s_setprio(1);
#pragma unroll
        for (int i = 0; i < 4; ++i)
#pragma unroll
            for (int j = 0; j < 4; ++j) {
                acc[i][j] = __builtin_amdgcn_mfma_f32_16x16x32_bf16(afh[i], bfh[j], acc[i][j], 0, 0, 0);
                acc[i][j] = __builtin_amdgcn_mfma_f32_16x16x32_bf16(afh[i], bfl[j], acc[i][j], 0, 0, 0);
                acc[i][j] = __builtin_amdgcn_mfma_f32_16x16x32_bf16(afl[i], bfh[j], acc[i][j], 0, 0, 0);
            }
        __builtin_amdgcn_s_setprio(0);

        // (e) split + ds_write A(t+1) into slot san (last read of san was
        //     step t-1, all waves past barrier(t) -> safe)
        {
            ushort_t* Aw = Awr + san * 8192;
            short8 h, l;
            split8(ax0, ax1, h, l);
            *(short8*)(Aw + c00 * 8) = h;  *(short8*)(Aw + 4096 + c00 * 8) = l;
            split8(ax2, ax3, h, l);
            *(short8*)(Aw + c01 * 8) = h;  *(short8*)(Aw + 4096 + c01 * 8) = l;
        }

        // (f,g,h) drain ds_writes; keep B(t+2)'s 4 DMA loads in flight
        asm volatile("s_waitcnt lgkmcnt(0)" ::: "memory");
        asm volatile("s_waitcnt vmcnt(4)" ::: "memory");
        __builtin_amdgcn_s_barrier();
        asm volatile("" ::: "memory");

        sa = san;
        sb = (sb + 1 == 3) ? 0 : sb + 1;
    }
    asm volatile("s_waitcnt vmcnt(0)" ::: "memory");   // drain wrap stages

    // ---- epilogue: C/D layout (m89-verified): col = lane&15, row = (lane>>4)*4 + r
    const int en = fr;
    const int emb = (lane >> 4) * 4;
#pragma unroll
    for (int j = 0; j < 4; ++j) {
        const size_t col = n0 + wn * 64 + j * 16 + en;
        const float bv = bias[col];
#pragma unroll
        for (int i = 0; i < 4; ++i) {
#pragma unroll
            for (int r = 0; r < 4; ++r) {
                const size_t row = m0 + wm * 64 + i * 16 + emb + r;
                const float o = acc[i][j][r] + bv;
                if (BF16OUT) ((ushort_t*)Yv)[row * N + col] = f2bf(o);
                else         ((float*)Yv)[row * N + col] = o;
            }
        }
    }
}

// ---------------------------------------------------------------------------
// K2 v3: corr via tiled-Gram MFMA, LDS-shared tile rings (see R2 notes).
// ---------------------------------------------------------------------------
__global__ __launch_bounds__(256)
void corr_mfma(const ushort_t* __restrict__ Qb, const ushort_t* __restrict__ Kb,
               float* __restrict__ corr) {
    __shared__ __align__(16) ushort_t Qlds[28 * 1024];  // 28 tiles x 2KB
    __shared__ __align__(16) ushort_t Klds[4 * 1024];   // 4 tiles x 2KB

    const int tid  = threadIdx.x;
    const int wave = tid >> 6;
    const int lane = tid & 63;
    const int bh = blockIdx.x;
    const int jq = blockIdx.y;
    const int b = bh >> 4, h = bh & 15;
    const int b0 = jq * 32;
    const int jbase = b0 + wave * 8;
    const int rr = lane & 15;
    const int cq = lane >> 4;
    const int s7 = rr & 7;

    const size_t slice = (size_t)b * L_SZ * D_SZ + (size_t)h * DK_SZ;
    const ushort_t* Qs = Qb + slice;
    const ushort_t* Ks = Kb + slice;
    const ushort_t* Qp = Qs + cq * 8;

    const int st  = tid & 127;
    const int sr  = st >> 3;
    const int sc  = (st & 7) ^ (sr & 7);
    const int whalf = (wave & 1) * 512;

    const int roff0 = rr * 64 + ((cq ^ s7) * 8);
    const int roff1 = roff0 ^ 32;

    float4v acc[8];
#pragma unroll
    for (int i = 0; i < 8; ++i) acc[i] = (float4v){0.f, 0.f, 0.f, 0.f};

    if (wave < 2) {
        for (int i = 0; i < 26; ++i) {
            const int qt = (b0 + 8 + i) & 127;
            gl_lds16(Qs + (size_t)(qt * 16 + sr) * 1024 + sc * 8,
                     &Qlds[i * 1024 + whalf]);
        }
    } else {
        for (int i = 0; i < 3; ++i) {
            gl_lds16(Ks + (size_t)(i * 16 + sr) * 1024 + sc * 8,
                     &Klds[i * 1024 + whalf]);
        }
    }

    short8 Wa[8], Wb[8];
#pragma unroll
    for (int i = 0; i < 8; ++i) {
        const size_t tq = (size_t)((((jbase + i) & 127) << 4) + rr) * D_SZ;
        Wa[i] = *(const short8*)(Qp + tq);
        Wb[i] = *(const short8*)(Qp + tq + 32);
    }

    asm volatile("s_waitcnt vmcnt(0)" ::: "memory");
    __builtin_amdgcn_s_barrier();
    asm volatile("" ::: "memory");

    short8 kb0 = *(const short8*)&Klds[roff0];
    short8 kb1 = *(const short8*)&Klds[roff1];

    int qsr = wave * 8;
    int qsw = 26;

    for (int s8 = 0; s8 < 128; s8 += 8) {
#pragma unroll
        for (int u = 0; u < 8; ++u) {
            const int s0 = s8 + u;
            if (wave < 2) {
                const int qt = (b0 + 34 + s0) & 127;
                gl_lds16(Qs + (size_t)(qt * 16 + sr) * 1024 + sc * 8,
                         &Qlds[qsw * 1024 + whalf]);
            } else {
                const int kt = (s0 + 3) & 127;
                gl_lds16(Ks + (size_t)(kt * 16 + sr) * 1024 + sc * 8,
                         &Klds[((s0 + 3) & 3) * 1024 + whalf]);
            }
            asm volatile("s_waitcnt vmcnt(2)" ::: "memory");
            __builtin_amdgcn_s_barrier();
            asm volatile("" ::: "memory");

            const int kslot = ((s0 + 1) & 3) * 1024;
            short8 nk0 = *(const short8*)&Klds[kslot + roff0];
            short8 nk1 = *(const short8*)&Klds[kslot + roff1];

            acc[0] = __builtin_amdgcn_mfma_f32_16x16x32_bf16(Wa[u], kb0, acc[0], 0, 0, 0);
            acc[0] = __builtin_amdgcn_mfma_f32_16x16x32_bf16(Wb[u], kb1, acc[0], 0, 0, 0);
            {
                const int qbse = qsr * 1024;
                Wa[u] = *(const short8*)&Qlds[qbse + roff0];
                Wb[u] = *(const short8*)&Qlds[qbse + roff1];
            }
#pragma unroll
            for (int jj = 1; jj < 8; ++jj) {
                acc[jj] = __builtin_amdgcn_mfma_f32_16x16x32_bf16(Wa[(u + jj) & 7], kb0, acc[jj], 0, 0, 0);
                acc[jj] = __builtin_amdgcn_mfma_f32_16x16x32_bf16(Wb[(u + jj) & 7], kb1, acc[jj], 0, 0, 0);
            }
            kb0 = nk0; kb1 = nk1;
            qsr = (qsr + 1 == 28) ? 0 : qsr + 1;
            qsw = (qsw + 1 == 28) ? 0 : qsw + 1;
        }
    }

    const int n = lane & 15;
    const int mb = (lane >> 4) * 4;
    float* cb = corr + (size_t)bh * L_SZ;
#pragma unroll
    for (int jj = 0; jj < 8; ++jj) {
        const int j16 = (jbase + jj) << 4;
#pragma unroll
        for (int r = 0; r < 4; ++r) {
            const int d = (j16 + mb + r - n) & (L_SZ - 1);
            atomicAdd(cb + d, acc[jj][r] * (1.0f / 64.0f));
        }
    }
}

// ---------------------------------------------------------------------------
// K3: per-(b,h) top-7 (tie -> lowest index) + softmax. One block per bh.
// ---------------------------------------------------------------------------
__global__ __launch_bounds__(256)
void topk_softmax(const float* __restrict__ corr, float* __restrict__ w,
                  int* __restrict__ delays) {
    __shared__ float cv[L_SZ];
    __shared__ float rv[256];
    __shared__ int   ri[256];
    __shared__ float topv[TOPK];
    __shared__ int   topi[TOPK];
    const int bh = blockIdx.x, tid = threadIdx.x;

    for (int i = tid; i < L_SZ; i += 256) cv[i] = corr[(size_t)bh * L_SZ + i];
    __syncthreads();

    for (int it = 0; it < TOPK; ++it) {
        float best = -INFINITY; int bi = 0;
        for (int i = tid; i < L_SZ; i += 256) {
            float x = cv[i];
            if (x > best) { best = x; bi = i; }
        }
        rv[tid] = best; ri[tid] = bi;
        __syncthreads();
        for (int stride = 128; stride > 0; stride >>= 1) {
            if (tid < stride) {
                float ov = rv[tid + stride]; int oi = ri[tid + stride];
                if (ov > rv[tid] || (ov == rv[tid] && oi < ri[tid])) {
                    rv[tid] = ov; ri[tid] = oi;
                }
            }
            __syncthreads();
        }
        if (tid == 0) {
            topv[it] = rv[0]; topi[it] = ri[0];
            cv[ri[0]] = -INFINITY;
        }
        __syncthreads();
    }

    if (tid == 0) {
        float mx = topv[0];
        float e[TOPK], s = 0.f;
#pragma unroll
        for (int i = 0; i < TOPK; ++i) { e[i] = expf(topv[i] - mx); s += e[i]; }
        const float inv = 1.0f / s;
#pragma unroll
        for (int i = 0; i < TOPK; ++i) {
            w[bh * TOPK + i] = e[i] * inv;
            delays[bh * TOPK + i] = topi[i];
        }
    }
}

// ---------------------------------------------------------------------------
// K4: mid[b,t,c] = sum_i w[bh,i] * V[b,(t - delay_i) % L, c]
// ---------------------------------------------------------------------------
__global__ __launch_bounds__(256)
void gather_combine(const float* __restrict__ V, const float* __restrict__ w,
                    const int* __restrict__ delays, float* __restrict__ mid) {
    const size_t g = (size_t)blockIdx.x * 256 + threadIdx.x;
    const int c4 = (int)(g & 255);
    const int t  = (int)((g >> 8) & (L_SZ - 1));
    const int b  = (int)(g >> 19);
    const int h  = c4 >> 4;
    const int bh = b * H_SZ + h;
    const size_t colbase = (size_t)b * L_SZ * D_SZ + (size_t)c4 * 4;

    float4 acc = {0.f, 0.f, 0.f, 0.f};
#pragma unroll
    for (int i = 0; i < TOPK; ++i) {
        const float wi = w[bh * TOPK + i];
        const int   di = delays[bh * TOPK + i];
        const int   ts = (t - di) & (L_SZ - 1);
        float4 v4 = *(const float4*)(V + colbase + (size_t)ts * D_SZ);
        acc.x += wi * v4.x; acc.y += wi * v4.y;
        acc.z += wi * v4.z; acc.w += wi * v4.w;
    }
    *(float4*)(mid + (size_t)b * L_SZ * D_SZ + (size_t)t * D_SZ + c4 * 4) = acc;
}

// ---------------------------------------------------------------------------
extern "C" void kernel_launch(void* const* d_in, const int* in_sizes, int n_in,
                              void* d_out, int out_size, void* d_ws, size_t ws_size,
                              hipStream_t stream) {
    const float* queries = (const float*)d_in[0];
    const float* keys    = (const float*)d_in[1];
    const float* values  = (const float*)d_in[2];
    const float* Wq = (const float*)d_in[3];
    const float* bq = (const float*)d_in[4];
    const float* Wk = (const float*)d_in[5];
    const float* bk = (const float*)d_in[6];
    const float* Wv = (const float*)d_in[7];
    const float* bv = (const float*)d_in[8];
    const float* Wo = (const float*)d_in[9];
    const float* bo = (const float*)d_in[10];

    const size_t NE = (size_t)M_SZ * D_SZ;          // 16.78M elements
    ushort_t* Qb16 = (ushort_t*)d_ws;               // 33.5 MB
    ushort_t* Kb16 = Qb16 + NE;                     // 33.5 MB
    float* Vb   = (float*)(Kb16 + NE);              // 67.1 MB
    float* corr = Vb + NE;                          // 1 MB (B*H*L fp32)
    float* wbuf = corr + (size_t)B_SZ * H_SZ * L_SZ;
    int*   dbuf = (int*)(wbuf + B_SZ * H_SZ * TOPK);
    ushort_t* WH = (ushort_t*)(dbuf + B_SZ * H_SZ * TOPK);  // 2 MB (reused)
    ushort_t* WL = WH + (size_t)D_SZ * D_SZ;                // 2 MB (reused)
    float* mid  = (float*)d_ws;  // aliases Qb16+Kb16 (67MB, dead after corr)

    dim3 ggemm(D_SZ / 128, M_SZ / 128);   // (8, 128)
    const int wn8 = D_SZ * D_SZ / 8;      // 131072

    split_fp32<<<(wn8 + 255) / 256, 256, 0, stream>>>(Wq, WH, WL, wn8);
    gemm_split_mfma<true><<<ggemm, 256, 0, stream>>>(queries, WH, WL, bq, Qb16, M_SZ, D_SZ, D_SZ);
    split_fp32<<<(wn8 + 255) / 256, 256, 0, stream>>>(Wk, WH, WL, wn8);
    gemm_split_mfma<true><<<ggemm, 256, 0, stream>>>(keys, WH, WL, bk, Kb16, M_SZ, D_SZ, D_SZ);
    split_fp32<<<(wn8 + 255) / 256, 256, 0, stream>>>(Wv, WH, WL, wn8);
    gemm_split_mfma<false><<<ggemm, 256, 0, stream>>>(values, WH, WL, bv, Vb, M_SZ, D_SZ, D_SZ);

    zero_f32<<<(B_SZ * H_SZ * L_SZ / 4 + 255) / 256, 256, 0, stream>>>(
        corr, B_SZ * H_SZ * L_SZ / 4);

    corr_mfma<<<dim3(B_SZ * H_SZ, 4), 256, 0, stream>>>(Qb16, Kb16, corr);

    topk_softmax<<<B_SZ * H_SZ, 256, 0, stream>>>(corr, wbuf, dbuf);

    gather_combine<<<(M_SZ * 256) / 256, 256, 0, stream>>>(Vb, wbuf, dbuf, mid);

    split_fp32<<<(wn8 + 255) / 256, 256, 0, stream>>>(Wo, WH, WL, wn8);
    gemm_split_mfma<false><<<ggemm, 256, 0, stream>>>(mid, WH, WL, bo, (float*)d_out, M_SZ, D_SZ, D_SZ);
}

// Round 6
// 785.916 us; speedup vs baseline: 1.1175x; 1.1175x over previous
//
#include <hip/hip_runtime.h>
#include <hip/hip_bf16.h>
#include <math.h>

#define B_SZ 8
#define L_SZ 2048
#define D_SZ 1024
#define H_SZ 16
#define DK_SZ 64
#define TOPK 7
#define M_SZ (B_SZ * L_SZ)   // 16384

typedef __attribute__((ext_vector_type(8))) short short8;
typedef __attribute__((ext_vector_type(4))) float float4v;
typedef unsigned short ushort_t;
typedef unsigned int uint_t;

__device__ __forceinline__ ushort_t f2bf(float x) {
    uint_t u = __float_as_uint(x);
    uint_t r = (u + 0x7fffu + ((u >> 16) & 1u)) >> 16;   // RNE
    return (ushort_t)r;
}

// Truncation split: x ~= hi + lo with |err| <= 2^-16 |x|.
__device__ __forceinline__ void split8(float4 x, float4 y, short8& hi, short8& lo) {
    float f[8] = {x.x, x.y, x.z, x.w, y.x, y.y, y.z, y.w};
#pragma unroll
    for (int i = 0; i < 8; ++i) {
        uint_t b = __float_as_uint(f[i]);
        hi[i] = (short)(b >> 16);
        float r = f[i] - __uint_as_float(b & 0xffff0000u);
        lo[i] = (short)(__float_as_uint(r) >> 16);
    }
}

// async global->LDS, 16B per lane. LDS dest must be wave-uniform base.
__device__ __forceinline__ void gl_lds16(const ushort_t* g, ushort_t* l) {
    __builtin_amdgcn_global_load_lds(
        (const __attribute__((address_space(1))) unsigned int*)g,
        (__attribute__((address_space(3))) unsigned int*)l, 16, 0, 0);
}

// ---------------------------------------------------------------------------
// K0: zero the corr accumulator (re-poisoned to 0xAA before every call)
// ---------------------------------------------------------------------------
__global__ __launch_bounds__(256)
void zero_f32(float* __restrict__ p, int n4) {
    int i = blockIdx.x * 256 + threadIdx.x;
    if (i < n4) ((float4*)p)[i] = make_float4(0.f, 0.f, 0.f, 0.f);
}

// ---------------------------------------------------------------------------
// K0b: split a fp32 array into hi/lo bf16 arrays (fallback, one W at a time).
// ---------------------------------------------------------------------------
__global__ __launch_bounds__(256)
void split_fp32(const float* __restrict__ X, ushort_t* __restrict__ hi,
                ushort_t* __restrict__ lo, int n8) {
    int i = blockIdx.x * 256 + threadIdx.x;
    if (i >= n8) return;
    float4 a = ((const float4*)X)[2 * i];
    float4 b = ((const float4*)X)[2 * i + 1];
    short8 h, l;
    split8(a, b, h, l);
    *(short8*)(hi + (size_t)i * 8) = h;
    *(short8*)(lo + (size_t)i * 8) = l;
}

// ---------------------------------------------------------------------------
// K0c: split all four 1024x1024 W matrices in ONE launch.
//   dst layout: [w][hi(1M) | lo(1M)] ushort, w in {Wq,Wk,Wv,Wo}.
//   grid (512, 4) x 256: exact cover, no bounds check.
// ---------------------------------------------------------------------------
__global__ __launch_bounds__(256)
void split_fp32_x4(const float* __restrict__ W0, const float* __restrict__ W1,
                   const float* __restrict__ W2, const float* __restrict__ W3,
                   ushort_t* __restrict__ dst) {
    const int w = blockIdx.y;
    const float* X = (w == 0) ? W0 : (w == 1) ? W1 : (w == 2) ? W2 : W3;
    ushort_t* hi = dst + (size_t)w * 2097152;
    ushort_t* lo = hi + 1048576;
    const int i = blockIdx.x * 256 + threadIdx.x;   // < 131072
    float4 a = ((const float4*)X)[2 * i];
    float4 b = ((const float4*)X)[2 * i + 1];
    short8 h, l;
    split8(a, b, h, l);
    *(short8*)(hi + (size_t)i * 8) = h;
    *(short8*)(lo + (size_t)i * 8) = l;
}

// ---------------------------------------------------------------------------
// K1: Y = X @ W^T + bias via split-bf16 MFMA (3 passes: hh + hl + lh).
//   PROVEN R4 version (131.5 us): 2-phase + T1 XCD-chunked swizzle.
//   R5's counted-vmcnt ring graft REGRESSED (165 us, conflicts 8.4M->12.7M):
//   consistent with the catalog regime-gate — T4/T5 only pay inside a true
//   8-phase role-split schedule; grafts onto 2-phase loops are null/negative.
//   Do NOT re-pipeline this kernel except as a full 8-phase 256^2 port.
// ---------------------------------------------------------------------------
template <bool BF16OUT>
__global__ __launch_bounds__(256)
void gemm_split_mfma(const float* __restrict__ X, const ushort_t* __restrict__ Whi,
                     const ushort_t* __restrict__ Wlo, const float* __restrict__ bias,
                     void* __restrict__ Yv, int M, int N, int K) {
    __shared__ __align__(16) short Ah[4][128][8];
    __shared__ __align__(16) short Al[4][128][8];
    __shared__ __align__(16) short Bh[4][128][8];
    __shared__ __align__(16) short Bl[4][128][8];

    const int tid = threadIdx.x;
    const int lane = tid & 63;
    const int wave = tid >> 6;
    const int wm = wave >> 1, wn = wave & 1;

    // T1 XCD-chunked swizzle (nwg = gridDim.x * gridDim.y, x = n-dim)
    const int flat = blockIdx.y * gridDim.x + blockIdx.x;
    const int cpx  = (gridDim.x * gridDim.y) >> 3;          // blocks per XCD
    const int swz  = (flat & 7) * cpx + (flat >> 3);
    const int bx   = swz % gridDim.x;                       // n-fastest
    const int by   = swz / gridDim.x;
    const size_t m0 = (size_t)by * 128;
    const size_t n0 = (size_t)bx * 128;

    const int srow = tid >> 1;
    const int g0 = (tid & 1) * 2;
    const int skseg = (tid & 1) * 16;

    const float*    Xp  = X   + (m0 + srow) * K + skseg;
    const ushort_t* Whp = Whi + (n0 + srow) * K + skseg;
    const ushort_t* Wlp = Wlo + (n0 + srow) * K + skseg;

    const int fr = lane & 15;
    const int fg = lane >> 4;

    float4 ax0 = *(const float4*)(Xp + 0);
    float4 ax1 = *(const float4*)(Xp + 4);
    float4 ax2 = *(const float4*)(Xp + 8);
    float4 ax3 = *(const float4*)(Xp + 12);
    short8 bh0 = *(const short8*)(Whp + 0);
    short8 bh1 = *(const short8*)(Whp + 8);
    short8 bl0 = *(const short8*)(Wlp + 0);
    short8 bl1 = *(const short8*)(Wlp + 8);

    float4v acc[4][4];
#pragma unroll
    for (int i = 0; i < 4; ++i)
#pragma unroll
        for (int j = 0; j < 4; ++j) acc[i][j] = (float4v){0.f, 0.f, 0.f, 0.f};

    for (int k0 = 0; k0 < K; k0 += 32) {
        __syncthreads();
        short8 h, l;
        split8(ax0, ax1, h, l);
        *(short8*)&Ah[g0][srow][0] = h;      *(short8*)&Al[g0][srow][0] = l;
        split8(ax2, ax3, h, l);
        *(short8*)&Ah[g0 + 1][srow][0] = h;  *(short8*)&Al[g0 + 1][srow][0] = l;
        *(short8*)&Bh[g0][srow][0] = bh0;    *(short8*)&Bh[g0 + 1][srow][0] = bh1;
        *(short8*)&Bl[g0][srow][0] = bl0;    *(short8*)&Bl[g0 + 1][srow][0] = bl1;
        __syncthreads();

        if (k0 + 32 < K) {
            ax0 = *(const float4*)(Xp + k0 + 32);
            ax1 = *(const float4*)(Xp + k0 + 36);
            ax2 = *(const float4*)(Xp + k0 + 40);
            ax3 = *(const float4*)(Xp + k0 + 44);
            bh0 = *(const short8*)(Whp + k0 + 32);
            bh1 = *(const short8*)(Whp + k0 + 40);
            bl0 = *(const short8*)(Wlp + k0 + 32);
            bl1 = *(const short8*)(Wlp + k0 + 40);
        }

        short8 afh[4], afl[4], bfh[4], bfl[4];
#pragma unroll
        for (int i = 0; i < 4; ++i) {
            const int r = wm * 64 + i * 16 + fr;
            afh[i] = *(const short8*)&Ah[fg][r][0];
            afl[i] = *(const short8*)&Al[fg][r][0];
        }
#pragma unroll
        for (int j = 0; j < 4; ++j) {
            const int r = wn * 64 + j * 16 + fr;
            bfh[j] = *(const short8*)&Bh[fg][r][0];
            bfl[j] = *(const short8*)&Bl[fg][r][0];
        }
#pragma unroll
        for (int i = 0; i < 4; ++i)
#pragma unroll
            for (int j = 0; j < 4; ++j) {
                acc[i][j] = __builtin_amdgcn_mfma_f32_16x16x32_bf16(afh[i], bfh[j], acc[i][j], 0, 0, 0);
                acc[i][j] = __builtin_amdgcn_mfma_f32_16x16x32_bf16(afh[i], bfl[j], acc[i][j], 0, 0, 0);
                acc[i][j] = __builtin_amdgcn_mfma_f32_16x16x32_bf16(afl[i], bfh[j], acc[i][j], 0, 0, 0);
            }
    }

    const int en = fr;
    const int emb = (lane >> 4) * 4;
#pragma unroll
    for (int j = 0; j < 4; ++j) {
        const size_t col = n0 + wn * 64 + j * 16 + en;
        const float bv = bias[col];
#pragma unroll
        for (int i = 0; i < 4; ++i) {
#pragma unroll
            for (int r = 0; r < 4; ++r) {
                const size_t row = m0 + wm * 64 + i * 16 + emb + r;
                const float o = acc[i][j][r] + bv;
                if (BF16OUT) ((ushort_t*)Yv)[row * N + col] = f2bf(o);
                else         ((float*)Yv)[row * N + col] = o;
            }
        }
    }
}

// ---------------------------------------------------------------------------
// K2 v3: corr via tiled-Gram MFMA, LDS-shared tile rings (proven since R2).
// ---------------------------------------------------------------------------
__global__ __launch_bounds__(256)
void corr_mfma(const ushort_t* __restrict__ Qb, const ushort_t* __restrict__ Kb,
               float* __restrict__ corr) {
    __shared__ __align__(16) ushort_t Qlds[28 * 1024];  // 28 tiles x 2KB
    __shared__ __align__(16) ushort_t Klds[4 * 1024];   // 4 tiles x 2KB

    const int tid  = threadIdx.x;
    const int wave = tid >> 6;
    const int lane = tid & 63;
    const int bh = blockIdx.x;
    const int jq = blockIdx.y;
    const int b = bh >> 4, h = bh & 15;
    const int b0 = jq * 32;
    const int jbase = b0 + wave * 8;
    const int rr = lane & 15;
    const int cq = lane >> 4;
    const int s7 = rr & 7;

    const size_t slice = (size_t)b * L_SZ * D_SZ + (size_t)h * DK_SZ;
    const ushort_t* Qs = Qb + slice;
    const ushort_t* Ks = Kb + slice;
    const ushort_t* Qp = Qs + cq * 8;

    const int st  = tid & 127;
    const int sr  = st >> 3;
    const int sc  = (st & 7) ^ (sr & 7);
    const int whalf = (wave & 1) * 512;

    const int roff0 = rr * 64 + ((cq ^ s7) * 8);
    const int roff1 = roff0 ^ 32;

    float4v acc[8];
#pragma unroll
    for (int i = 0; i < 8; ++i) acc[i] = (float4v){0.f, 0.f, 0.f, 0.f};

    if (wave < 2) {
        for (int i = 0; i < 26; ++i) {
            const int qt = (b0 + 8 + i) & 127;
            gl_lds16(Qs + (size_t)(qt * 16 + sr) * 1024 + sc * 8,
                     &Qlds[i * 1024 + whalf]);
        }
    } else {
        for (int i = 0; i < 3; ++i) {
            gl_lds16(Ks + (size_t)(i * 16 + sr) * 1024 + sc * 8,
                     &Klds[i * 1024 + whalf]);
        }
    }

    short8 Wa[8], Wb[8];
#pragma unroll
    for (int i = 0; i < 8; ++i) {
        const size_t tq = (size_t)((((jbase + i) & 127) << 4) + rr) * D_SZ;
        Wa[i] = *(const short8*)(Qp + tq);
        Wb[i] = *(const short8*)(Qp + tq + 32);
    }

    asm volatile("s_waitcnt vmcnt(0)" ::: "memory");
    __builtin_amdgcn_s_barrier();
    asm volatile("" ::: "memory");

    short8 kb0 = *(const short8*)&Klds[roff0];
    short8 kb1 = *(const short8*)&Klds[roff1];

    int qsr = wave * 8;
    int qsw = 26;

    for (int s8 = 0; s8 < 128; s8 += 8) {
#pragma unroll
        for (int u = 0; u < 8; ++u) {
            const int s0 = s8 + u;
            if (wave < 2) {
                const int qt = (b0 + 34 + s0) & 127;
                gl_lds16(Qs + (size_t)(qt * 16 + sr) * 1024 + sc * 8,
                         &Qlds[qsw * 1024 + whalf]);
            } else {
                const int kt = (s0 + 3) & 127;
                gl_lds16(Ks + (size_t)(kt * 16 + sr) * 1024 + sc * 8,
                         &Klds[((s0 + 3) & 3) * 1024 + whalf]);
            }
            asm volatile("s_waitcnt vmcnt(2)" ::: "memory");
            __builtin_amdgcn_s_barrier();
            asm volatile("" ::: "memory");

            const int kslot = ((s0 + 1) & 3) * 1024;
            short8 nk0 = *(const short8*)&Klds[kslot + roff0];
            short8 nk1 = *(const short8*)&Klds[kslot + roff1];

            acc[0] = __builtin_amdgcn_mfma_f32_16x16x32_bf16(Wa[u], kb0, acc[0], 0, 0, 0);
            acc[0] = __builtin_amdgcn_mfma_f32_16x16x32_bf16(Wb[u], kb1, acc[0], 0, 0, 0);
            {
                const int qbse = qsr * 1024;
                Wa[u] = *(const short8*)&Qlds[qbse + roff0];
                Wb[u] = *(const short8*)&Qlds[qbse + roff1];
            }
#pragma unroll
            for (int jj = 1; jj < 8; ++jj) {
                acc[jj] = __builtin_amdgcn_mfma_f32_16x16x32_bf16(Wa[(u + jj) & 7], kb0, acc[jj], 0, 0, 0);
                acc[jj] = __builtin_amdgcn_mfma_f32_16x16x32_bf16(Wb[(u + jj) & 7], kb1, acc[jj], 0, 0, 0);
            }
            kb0 = nk0; kb1 = nk1;
            qsr = (qsr + 1 == 28) ? 0 : qsr + 1;
            qsw = (qsw + 1 == 28) ? 0 : qsw + 1;
        }
    }

    const int n = lane & 15;
    const int mb = (lane >> 4) * 4;
    float* cb = corr + (size_t)bh * L_SZ;
#pragma unroll
    for (int jj = 0; jj < 8; ++jj) {
        const int j16 = (jbase + jj) << 4;
#pragma unroll
        for (int r = 0; r < 4; ++r) {
            const int d = (j16 + mb + r - n) & (L_SZ - 1);
            atomicAdd(cb + d, acc[jj][r] * (1.0f / 64.0f));
        }
    }
}

// ---------------------------------------------------------------------------
// K3 v2: per-(b,h) top-7 + softmax. One block per bh.
//   Wave-shuffle reduction: per-iter barriers 8 -> 2 (identical selection
//   predicate: strictly-greater value, then lowest index -> bit-identical).
// ---------------------------------------------------------------------------
__global__ __launch_bounds__(256)
void topk_softmax(const float* __restrict__ corr, float* __restrict__ w,
                  int* __restrict__ delays) {
    __shared__ float cv[L_SZ];
    __shared__ float wvv[4];
    __shared__ int   wvi[4];
    __shared__ float topv[TOPK];
    __shared__ int   topi[TOPK];
    const int bh = blockIdx.x, tid = threadIdx.x;
    const int lane = tid & 63, wid = tid >> 6;

    for (int i = tid; i < L_SZ; i += 256) cv[i] = corr[(size_t)bh * L_SZ + i];
    __syncthreads();

    for (int it = 0; it < TOPK; ++it) {
        float best = -INFINITY; int bi = 0;
        for (int i = tid; i < L_SZ; i += 256) {
            float x = cv[i];
            if (x > best) { best = x; bi = i; }   // ascending i: ties keep lowest
        }
#pragma unroll
        for (int off = 32; off > 0; off >>= 1) {
            float ov = __shfl_down(best, off);
            int   oi = __shfl_down(bi, off);
            if (ov > best || (ov == best && oi < bi)) { best = ov; bi = oi; }
        }
        if (lane == 0) { wvv[wid] = best; wvi[wid] = bi; }
        __syncthreads();
        if (tid == 0) {
            float bb = wvv[0]; int bbi = wvi[0];
#pragma unroll
            for (int k = 1; k < 4; ++k)
                if (wvv[k] > bb || (wvv[k] == bb && wvi[k] < bbi)) { bb = wvv[k]; bbi = wvi[k]; }
            topv[it] = bb; topi[it] = bbi;
            cv[bbi] = -INFINITY;
        }
        __syncthreads();
    }

    if (tid == 0) {
        float mx = topv[0];
        float e[TOPK], s = 0.f;
#pragma unroll
        for (int i = 0; i < TOPK; ++i) { e[i] = expf(topv[i] - mx); s += e[i]; }
        const float inv = 1.0f / s;
#pragma unroll
        for (int i = 0; i < TOPK; ++i) {
            w[bh * TOPK + i] = e[i] * inv;
            delays[bh * TOPK + i] = topi[i];
        }
    }
}

// ---------------------------------------------------------------------------
// K4: mid[b,t,c] = sum_i w[bh,i] * V[b,(t - delay_i) % L, c]
// ---------------------------------------------------------------------------
__global__ __launch_bounds__(256)
void gather_combine(const float* __restrict__ V, const float* __restrict__ w,
                    const int* __restrict__ delays, float* __restrict__ mid) {
    const size_t g = (size_t)blockIdx.x * 256 + threadIdx.x;
    const int c4 = (int)(g & 255);
    const int t  = (int)((g >> 8) & (L_SZ - 1));
    const int b  = (int)(g >> 19);
    const int h  = c4 >> 4;
    const int bh = b * H_SZ + h;
    const size_t colbase = (size_t)b * L_SZ * D_SZ + (size_t)c4 * 4;

    float4 acc = {0.f, 0.f, 0.f, 0.f};
#pragma unroll
    for (int i = 0; i < TOPK; ++i) {
        const float wi = w[bh * TOPK + i];
        const int   di = delays[bh * TOPK + i];
        const int   ts = (t - di) & (L_SZ - 1);
        float4 v4 = *(const float4*)(V + colbase + (size_t)ts * D_SZ);
        acc.x += wi * v4.x; acc.y += wi * v4.y;
        acc.z += wi * v4.z; acc.w += wi * v4.w;
    }
    *(float4*)(mid + (size_t)b * L_SZ * D_SZ + (size_t)t * D_SZ + c4 * 4) = acc;
}

// ---------------------------------------------------------------------------
extern "C" void kernel_launch(void* const* d_in, const int* in_sizes, int n_in,
                              void* d_out, int out_size, void* d_ws, size_t ws_size,
                              hipStream_t stream) {
    const float* queries = (const float*)d_in[0];
    const float* keys    = (const float*)d_in[1];
    const float* values  = (const float*)d_in[2];
    const float* Wq = (const float*)d_in[3];
    const float* bq = (const float*)d_in[4];
    const float* Wk = (const float*)d_in[5];
    const float* bk = (const float*)d_in[6];
    const float* Wv = (const float*)d_in[7];
    const float* bv = (const float*)d_in[8];
    const float* Wo = (const float*)d_in[9];
    const float* bo = (const float*)d_in[10];

    const size_t NE = (size_t)M_SZ * D_SZ;          // 16.78M elements
    const size_t WNE = (size_t)D_SZ * D_SZ;         // 1,048,576
    ushort_t* Qb16 = (ushort_t*)d_ws;               // 33.5 MB
    ushort_t* Kb16 = Qb16 + NE;                     // 33.5 MB
    float* Vb   = (float*)(Kb16 + NE);              // 67.1 MB
    float* corr = Vb + NE;                          // 1 MB (B*H*L fp32)
    float* wbuf = corr + (size_t)B_SZ * H_SZ * L_SZ;
    int*   dbuf = (int*)(wbuf + B_SZ * H_SZ * TOPK);
    ushort_t* WS = (ushort_t*)(dbuf + B_SZ * H_SZ * TOPK);  // W split region
    float* mid  = (float*)d_ws;  // aliases Qb16+Kb16 (67MB, dead after corr)

    dim3 ggemm(D_SZ / 128, M_SZ / 128);   // (8, 128)
    const int wn8 = (int)(WNE / 8);       // 131072

    // batched W-split needs 4 x (hi+lo) = 16 MB at WS; guard on ws_size.
    const size_t ws_off  = (size_t)((char*)WS - (char*)d_ws);
    const bool batched = ws_size >= ws_off + 4 * 2 * WNE * sizeof(ushort_t);

    if (batched) {
        split_fp32_x4<<<dim3(512, 4), 256, 0, stream>>>(Wq, Wk, Wv, Wo, WS);
        gemm_split_mfma<true><<<ggemm, 256, 0, stream>>>(
            queries, WS + 0 * 2 * WNE, WS + 0 * 2 * WNE + WNE, bq, Qb16, M_SZ, D_SZ, D_SZ);
        gemm_split_mfma<true><<<ggemm, 256, 0, stream>>>(
            keys,    WS + 1 * 2 * WNE, WS + 1 * 2 * WNE + WNE, bk, Kb16, M_SZ, D_SZ, D_SZ);
        gemm_split_mfma<false><<<ggemm, 256, 0, stream>>>(
            values,  WS + 2 * 2 * WNE, WS + 2 * 2 * WNE + WNE, bv, Vb, M_SZ, D_SZ, D_SZ);
    } else {
        ushort_t* WH = WS;
        ushort_t* WL = WS + WNE;
        split_fp32<<<(wn8 + 255) / 256, 256, 0, stream>>>(Wq, WH, WL, wn8);
        gemm_split_mfma<true><<<ggemm, 256, 0, stream>>>(queries, WH, WL, bq, Qb16, M_SZ, D_SZ, D_SZ);
        split_fp32<<<(wn8 + 255) / 256, 256, 0, stream>>>(Wk, WH, WL, wn8);
        gemm_split_mfma<true><<<ggemm, 256, 0, stream>>>(keys, WH, WL, bk, Kb16, M_SZ, D_SZ, D_SZ);
        split_fp32<<<(wn8 + 255) / 256, 256, 0, stream>>>(Wv, WH, WL, wn8);
        gemm_split_mfma<false><<<ggemm, 256, 0, stream>>>(values, WH, WL, bv, Vb, M_SZ, D_SZ, D_SZ);
    }

    zero_f32<<<(B_SZ * H_SZ * L_SZ / 4 + 255) / 256, 256, 0, stream>>>(
        corr, B_SZ * H_SZ * L_SZ / 4);

    corr_mfma<<<dim3(B_SZ * H_SZ, 4), 256, 0, stream>>>(Qb16, Kb16, corr);

    topk_softmax<<<B_SZ * H_SZ, 256, 0, stream>>>(corr, wbuf, dbuf);

    gather_combine<<<(M_SZ * 256) / 256, 256, 0, stream>>>(Vb, wbuf, dbuf, mid);

    if (batched) {
        gemm_split_mfma<false><<<ggemm, 256, 0, stream>>>(
            mid, WS + 3 * 2 * WNE, WS + 3 * 2 * WNE + WNE, bo, (float*)d_out, M_SZ, D_SZ, D_SZ);
    } else {
        ushort_t* WH = WS;
        ushort_t* WL = WS + WNE;
        split_fp32<<<(wn8 + 255) / 256, 256, 0, stream>>>(Wo, WH, WL, wn8);
        gemm_split_mfma<false><<<ggemm, 256, 0, stream>>>(mid, WH, WL, bo, (float*)d_out, M_SZ, D_SZ, D_SZ);
    }
}

// Round 7
// 775.025 us; speedup vs baseline: 1.1332x; 1.0141x over previous
//
#include <hip/hip_runtime.h>
#include <hip/hip_bf16.h>
#include <math.h>

#define B_SZ 8
#define L_SZ 2048
#define D_SZ 1024
#define H_SZ 16
#define DK_SZ 64
#define TOPK 7
#define M_SZ (B_SZ * L_SZ)   // 16384

typedef __attribute__((ext_vector_type(8))) short short8;
typedef __attribute__((ext_vector_type(4))) float float4v;
typedef unsigned short ushort_t;
typedef unsigned int uint_t;

__device__ __forceinline__ ushort_t f2bf(float x) {
    uint_t u = __float_as_uint(x);
    uint_t r = (u + 0x7fffu + ((u >> 16) & 1u)) >> 16;   // RNE
    return (ushort_t)r;
}

// Truncation split: x ~= hi + lo with |err| <= 2^-16 |x|.
__device__ __forceinline__ void split8(float4 x, float4 y, short8& hi, short8& lo) {
    float f[8] = {x.x, x.y, x.z, x.w, y.x, y.y, y.z, y.w};
#pragma unroll
    for (int i = 0; i < 8; ++i) {
        uint_t b = __float_as_uint(f[i]);
        hi[i] = (short)(b >> 16);
        float r = f[i] - __uint_as_float(b & 0xffff0000u);
        lo[i] = (short)(__float_as_uint(r) >> 16);
    }
}

// async global->LDS, 16B per lane. LDS dest must be wave-uniform base.
__device__ __forceinline__ void gl_lds16(const ushort_t* g, ushort_t* l) {
    __builtin_amdgcn_global_load_lds(
        (const __attribute__((address_space(1))) unsigned int*)g,
        (__attribute__((address_space(3))) unsigned int*)l, 16, 0, 0);
}

// ---------------------------------------------------------------------------
// K0: zero the corr accumulator (re-poisoned to 0xAA before every call)
// ---------------------------------------------------------------------------
__global__ __launch_bounds__(256)
void zero_f32(float* __restrict__ p, int n4) {
    int i = blockIdx.x * 256 + threadIdx.x;
    if (i < n4) ((float4*)p)[i] = make_float4(0.f, 0.f, 0.f, 0.f);
}

// ---------------------------------------------------------------------------
// K0b: split a fp32 array into hi/lo bf16 arrays (fallback, one W at a time).
// ---------------------------------------------------------------------------
__global__ __launch_bounds__(256)
void split_fp32(const float* __restrict__ X, ushort_t* __restrict__ hi,
                ushort_t* __restrict__ lo, int n8) {
    int i = blockIdx.x * 256 + threadIdx.x;
    if (i >= n8) return;
    float4 a = ((const float4*)X)[2 * i];
    float4 b = ((const float4*)X)[2 * i + 1];
    short8 h, l;
    split8(a, b, h, l);
    *(short8*)(hi + (size_t)i * 8) = h;
    *(short8*)(lo + (size_t)i * 8) = l;
}

// ---------------------------------------------------------------------------
// K0c: split all four 1024x1024 W matrices in ONE launch.
// ---------------------------------------------------------------------------
__global__ __launch_bounds__(256)
void split_fp32_x4(const float* __restrict__ W0, const float* __restrict__ W1,
                   const float* __restrict__ W2, const float* __restrict__ W3,
                   ushort_t* __restrict__ dst) {
    const int w = blockIdx.y;
    const float* X = (w == 0) ? W0 : (w == 1) ? W1 : (w == 2) ? W2 : W3;
    ushort_t* hi = dst + (size_t)w * 2097152;
    ushort_t* lo = hi + 1048576;
    const int i = blockIdx.x * 256 + threadIdx.x;   // < 131072
    float4 a = ((const float4*)X)[2 * i];
    float4 b = ((const float4*)X)[2 * i + 1];
    short8 h, l;
    split8(a, b, h, l);
    *(short8*)(hi + (size_t)i * 8) = h;
    *(short8*)(lo + (size_t)i * 8) = l;
}

// ---------------------------------------------------------------------------
// K1 v4: Y = X @ W^T + bias, split-bf16 MFMA (hh+hl+lh), 256^2 tile, BK=32.
//   512 thr / 8 waves (2M x 4N), wave tile 128x64, acc 8x4 frags.
//   Per K-tile per CU: 768 MFMA ~= 3724 cyc cover (5x the 128^2 step) so
//   tile t+1's A-fp32 reg loads + B global_load_lds DMA, issued at the TOP
//   of iteration t, are fully landed when the single end-of-tile
//   __syncthreads (vmcnt0) drains them -> no exposed latency (fixes R5's
//   failure: 700-cyc cover at 128^2/BK=32).
//   LDS rows = [hi(32bf16) | lo(32bf16)] = 128 B = 8 granules, XOR swizzle
//   slot = g ^ (row&7) ^ ((row>>3&1)<<2): frag reads 2-way (free), A-writes
//   4-way. B staged via DMA (linear dest) with inverse-swizzled SOURCE
//   granule (rule #21, proven in corr_mfma). lo offset = hi offset ^ 32.
//   3 phases (hh/hl/lh) split by raw s_barrier + setprio (role-split).
//   T1 XCD swizzle: 32 blocks/XCD, n-fastest decode -> A-panel L2 reuse.
//   Accumulation order per acc element identical to the 128^2 kernel
//   (same BK=32 tiling, hh->hl->lh per tile) -> bit-identical output.
// ---------------------------------------------------------------------------
template <bool BF16OUT>
__global__ __launch_bounds__(512, 2)
void gemm256(const float* __restrict__ X, const ushort_t* __restrict__ Whi,
             const ushort_t* __restrict__ Wlo, const float* __restrict__ bias,
             void* __restrict__ Yv) {
    __shared__ __align__(16) ushort_t Ab[2][256][64];   // 64 KB (hi|lo rows)
    __shared__ __align__(16) ushort_t Bb[2][256][64];   // 64 KB

    const int tid = threadIdx.x;
    const int lane = tid & 63;
    const int wave = tid >> 6;          // 0..7
    const int wm = wave >> 2;           // 0..1  (M half)
    const int wn = wave & 3;            // 0..3  (N quarter)

    // T1 XCD swizzle: grid (4,64) = 256 blocks, 32/XCD, n-fastest decode
    const int flat = blockIdx.y * 4 + blockIdx.x;
    const int swz  = (flat & 7) * 32 + (flat >> 3);
    const size_t n0 = (size_t)(swz & 3) * 256;
    const size_t m0 = (size_t)(swz >> 2) * 256;

    // ---- A staging: thread -> (row, k-half of 16)
    const int arow = tid >> 1;
    const int ah   = tid & 1;
    const float* Xp = X + (m0 + arow) * D_SZ + ah * 16;
    const int rswA = (arow & 7) ^ (((arow >> 3) & 1) << 2);
    const int sh0 = (2 * ah) ^ rswA;          // hi granule 2ah slot
    const int sh1 = (2 * ah + 1) ^ rswA;      // hi granule 2ah+1 slot
    ushort_t* Awr = &Ab[0][arow][0];          // + buf*16384

    // ---- B staging: 4 x 16B DMA per thread, linear dest, swizzled source
    const ushort_t* bsrc[4];
    int bdst[4];
#pragma unroll
    for (int i = 0; i < 4; ++i) {
        const int G   = i * 512 + tid;        // linear granule 0..2047
        const int row = G >> 3;
        const int slt = G & 7;
        const int g   = slt ^ (row & 7) ^ (((row >> 3) & 1) << 2);
        bsrc[i] = ((g < 4) ? Whi : Wlo) + (n0 + row) * D_SZ + (g & 3) * 8;
        bdst[i] = G * 8;
    }

    // ---- fragment read offsets (ushort units); lo = hi ^ 32
    const int fr = lane & 15;
    const int fg = lane >> 4;                 // k-granule 0..3
    int offA[8], offB[4];
#pragma unroll
    for (int f = 0; f < 8; ++f) {
        const int r = wm * 128 + f * 16 + fr;
        offA[f] = r * 64 + (fg ^ ((r & 7) ^ (((r >> 3) & 1) << 2))) * 8;
    }
#pragma unroll
    for (int j = 0; j < 4; ++j) {
        const int r = wn * 64 + j * 16 + fr;
        offB[j] = r * 64 + (fg ^ ((r & 7) ^ (((r >> 3) & 1) << 2))) * 8;
    }

    float4v acc[8][4];
#pragma unroll
    for (int f = 0; f < 8; ++f)
#pragma unroll
        for (int j = 0; j < 4; ++j) acc[f][j] = (float4v){0.f, 0.f, 0.f, 0.f};

    // ---- prologue: tile 0
    float4 ax0 = *(const float4*)(Xp + 0);
    float4 ax1 = *(const float4*)(Xp + 4);
    float4 ax2 = *(const float4*)(Xp + 8);
    float4 ax3 = *(const float4*)(Xp + 12);
#pragma unroll
    for (int i = 0; i < 4; ++i) gl_lds16(bsrc[i], &Bb[0][0][0] + bdst[i]);
    {
        short8 h, l;
        split8(ax0, ax1, h, l);
        *(short8*)(Awr + sh0 * 8) = h;  *(short8*)(Awr + (sh0 ^ 4) * 8) = l;
        split8(ax2, ax3, h, l);
        *(short8*)(Awr + sh1 * 8) = h;  *(short8*)(Awr + (sh1 ^ 4) * 8) = l;
    }
    __syncthreads();

    for (int t = 0; t < 32; ++t) {
        const int cur = t & 1;
        const ushort_t* Ac = &Ab[cur][0][0];
        const ushort_t* Bc = &Bb[cur][0][0];
        const bool pf = (t + 1 < 32);

        // issue-early: tile t+1 A-fp32 -> regs, B -> DMA into buf cur^1
        if (pf) {
            const int kn = (t + 1) * 32;
            ax0 = *(const float4*)(Xp + kn + 0);
            ax1 = *(const float4*)(Xp + kn + 4);
            ax2 = *(const float4*)(Xp + kn + 8);
            ax3 = *(const float4*)(Xp + kn + 12);
            ushort_t* Bn = &Bb[cur ^ 1][0][0];
#pragma unroll
            for (int i = 0; i < 4; ++i) gl_lds16(bsrc[i] + kn, Bn + bdst[i]);
        }

        // P0: hh
        short8 fAh[8], fBh[4];
#pragma unroll
        for (int f = 0; f < 8; ++f) fAh[f] = *(const short8*)(Ac + offA[f]);
#pragma unroll
        for (int j = 0; j < 4; ++j) fBh[j] = *(const short8*)(Bc + offB[j]);
        __builtin_amdgcn_s_setprio(1);
#pragma unroll
        for (int f = 0; f < 8; ++f)
#pragma unroll
            for (int j = 0; j < 4; ++j)
                acc[f][j] = __builtin_amdgcn_mfma_f32_16x16x32_bf16(fAh[f], fBh[j], acc[f][j], 0, 0, 0);
        __builtin_amdgcn_s_setprio(0);
        __builtin_amdgcn_s_barrier();

        // P1: hl
        short8 fBl[4];
#pragma unroll
        for (int j = 0; j < 4; ++j) fBl[j] = *(const short8*)(Bc + (offB[j] ^ 32));
        __builtin_amdgcn_s_setprio(1);
#pragma unroll
        for (int f = 0; f < 8; ++f)
#pragma unroll
            for (int j = 0; j < 4; ++j)
                acc[f][j] = __builtin_amdgcn_mfma_f32_16x16x32_bf16(fAh[f], fBl[j], acc[f][j], 0, 0, 0);
        __builtin_amdgcn_s_setprio(0);
        __builtin_amdgcn_s_barrier();

        // P2: lh
        short8 fAl[8];
#pragma unroll
        for (int f = 0; f < 8; ++f) fAl[f] = *(const short8*)(Ac + (offA[f] ^ 32));
        __builtin_amdgcn_s_setprio(1);
#pragma unroll
        for (int f = 0; f < 8; ++f)
#pragma unroll
            for (int j = 0; j < 4; ++j)
                acc[f][j] = __builtin_amdgcn_mfma_f32_16x16x32_bf16(fAl[f], fBh[j], acc[f][j], 0, 0, 0);
        __builtin_amdgcn_s_setprio(0);

        // split + write A(t+1) into buf cur^1
        if (pf) {
            ushort_t* Aw = Awr + (cur ^ 1) * 16384;
            short8 h, l;
            split8(ax0, ax1, h, l);
            *(short8*)(Aw + sh0 * 8) = h;  *(short8*)(Aw + (sh0 ^ 4) * 8) = l;
            split8(ax2, ax3, h, l);
            *(short8*)(Aw + sh1 * 8) = h;  *(short8*)(Aw + (sh1 ^ 4) * 8) = l;
        }
        __syncthreads();   // drains A ds_writes + B DMA (issued ~3.5k cyc ago)
    }

    // ---- epilogue: C/D layout (m89-verified): col = lane&15, row = (lane>>4)*4 + r
    const int emb = (lane >> 4) * 4;
#pragma unroll
    for (int j = 0; j < 4; ++j) {
        const size_t col = n0 + wn * 64 + j * 16 + fr;
        const float bv = bias[col];
#pragma unroll
        for (int f = 0; f < 8; ++f) {
#pragma unroll
            for (int r = 0; r < 4; ++r) {
                const size_t row = m0 + wm * 128 + f * 16 + emb + r;
                const float o = acc[f][j][r] + bv;
                if (BF16OUT) ((ushort_t*)Yv)[row * D_SZ + col] = f2bf(o);
                else         ((float*)Yv)[row * D_SZ + col] = o;
            }
        }
    }
}

// ---------------------------------------------------------------------------
// K2 v3: corr via tiled-Gram MFMA, LDS-shared tile rings (proven since R2).
// ---------------------------------------------------------------------------
__global__ __launch_bounds__(256)
void corr_mfma(const ushort_t* __restrict__ Qb, const ushort_t* __restrict__ Kb,
               float* __restrict__ corr) {
    __shared__ __align__(16) ushort_t Qlds[28 * 1024];  // 28 tiles x 2KB
    __shared__ __align__(16) ushort_t Klds[4 * 1024];   // 4 tiles x 2KB

    const int tid  = threadIdx.x;
    const int wave = tid >> 6;
    const int lane = tid & 63;
    const int bh = blockIdx.x;
    const int jq = blockIdx.y;
    const int b = bh >> 4, h = bh & 15;
    const int b0 = jq * 32;
    const int jbase = b0 + wave * 8;
    const int rr = lane & 15;
    const int cq = lane >> 4;
    const int s7 = rr & 7;

    const size_t slice = (size_t)b * L_SZ * D_SZ + (size_t)h * DK_SZ;
    const ushort_t* Qs = Qb + slice;
    const ushort_t* Ks = Kb + slice;
    const ushort_t* Qp = Qs + cq * 8;

    const int st  = tid & 127;
    const int sr  = st >> 3;
    const int sc  = (st & 7) ^ (sr & 7);
    const int whalf = (wave & 1) * 512;

    const int roff0 = rr * 64 + ((cq ^ s7) * 8);
    const int roff1 = roff0 ^ 32;

    float4v acc[8];
#pragma unroll
    for (int i = 0; i < 8; ++i) acc[i] = (float4v){0.f, 0.f, 0.f, 0.f};

    if (wave < 2) {
        for (int i = 0; i < 26; ++i) {
            const int qt = (b0 + 8 + i) & 127;
            gl_lds16(Qs + (size_t)(qt * 16 + sr) * 1024 + sc * 8,
                     &Qlds[i * 1024 + whalf]);
        }
    } else {
        for (int i = 0; i < 3; ++i) {
            gl_lds16(Ks + (size_t)(i * 16 + sr) * 1024 + sc * 8,
                     &Klds[i * 1024 + whalf]);
        }
    }

    short8 Wa[8], Wb[8];
#pragma unroll
    for (int i = 0; i < 8; ++i) {
        const size_t tq = (size_t)((((jbase + i) & 127) << 4) + rr) * D_SZ;
        Wa[i] = *(const short8*)(Qp + tq);
        Wb[i] = *(const short8*)(Qp + tq + 32);
    }

    asm volatile("s_waitcnt vmcnt(0)" ::: "memory");
    __builtin_amdgcn_s_barrier();
    asm volatile("" ::: "memory");

    short8 kb0 = *(const short8*)&Klds[roff0];
    short8 kb1 = *(const short8*)&Klds[roff1];

    int qsr = wave * 8;
    int qsw = 26;

    for (int s8 = 0; s8 < 128; s8 += 8) {
#pragma unroll
        for (int u = 0; u < 8; ++u) {
            const int s0 = s8 + u;
            if (wave < 2) {
                const int qt = (b0 + 34 + s0) & 127;
                gl_lds16(Qs + (size_t)(qt * 16 + sr) * 1024 + sc * 8,
                         &Qlds[qsw * 1024 + whalf]);
            } else {
                const int kt = (s0 + 3) & 127;
                gl_lds16(Ks + (size_t)(kt * 16 + sr) * 1024 + sc * 8,
                         &Klds[((s0 + 3) & 3) * 1024 + whalf]);
            }
            asm volatile("s_waitcnt vmcnt(2)" ::: "memory");
            __builtin_amdgcn_s_barrier();
            asm volatile("" ::: "memory");

            const int kslot = ((s0 + 1) & 3) * 1024;
            short8 nk0 = *(const short8*)&Klds[kslot + roff0];
            short8 nk1 = *(const short8*)&Klds[kslot + roff1];

            acc[0] = __builtin_amdgcn_mfma_f32_16x16x32_bf16(Wa[u], kb0, acc[0], 0, 0, 0);
            acc[0] = __builtin_amdgcn_mfma_f32_16x16x32_bf16(Wb[u], kb1, acc[0], 0, 0, 0);
            {
                const int qbse = qsr * 1024;
                Wa[u] = *(const short8*)&Qlds[qbse + roff0];
                Wb[u] = *(const short8*)&Qlds[qbse + roff1];
            }
#pragma unroll
            for (int jj = 1; jj < 8; ++jj) {
                acc[jj] = __builtin_amdgcn_mfma_f32_16x16x32_bf16(Wa[(u + jj) & 7], kb0, acc[jj], 0, 0, 0);
                acc[jj] = __builtin_amdgcn_mfma_f32_16x16x32_bf16(Wb[(u + jj) & 7], kb1, acc[jj], 0, 0, 0);
            }
            kb0 = nk0; kb1 = nk1;
            qsr = (qsr + 1 == 28) ? 0 : qsr + 1;
            qsw = (qsw + 1 == 28) ? 0 : qsw + 1;
        }
    }

    const int n = lane & 15;
    const int mb = (lane >> 4) * 4;
    float* cb = corr + (size_t)bh * L_SZ;
#pragma unroll
    for (int jj = 0; jj < 8; ++jj) {
        const int j16 = (jbase + jj) << 4;
#pragma unroll
        for (int r = 0; r < 4; ++r) {
            const int d = (j16 + mb + r - n) & (L_SZ - 1);
            atomicAdd(cb + d, acc[jj][r] * (1.0f / 64.0f));
        }
    }
}

// ---------------------------------------------------------------------------
// K3 v2: per-(b,h) top-7 + softmax (wave-shuffle reduce). One block per bh.
// ---------------------------------------------------------------------------
__global__ __launch_bounds__(256)
void topk_softmax(const float* __restrict__ corr, float* __restrict__ w,
                  int* __restrict__ delays) {
    __shared__ float cv[L_SZ];
    __shared__ float wvv[4];
    __shared__ int   wvi[4];
    __shared__ float topv[TOPK];
    __shared__ int   topi[TOPK];
    const int bh = blockIdx.x, tid = threadIdx.x;
    const int lane = tid & 63, wid = tid >> 6;

    for (int i = tid; i < L_SZ; i += 256) cv[i] = corr[(size_t)bh * L_SZ + i];
    __syncthreads();

    for (int it = 0; it < TOPK; ++it) {
        float best = -INFINITY; int bi = 0;
        for (int i = tid; i < L_SZ; i += 256) {
            float x = cv[i];
            if (x > best) { best = x; bi = i; }
        }
#pragma unroll
        for (int off = 32; off > 0; off >>= 1) {
            float ov = __shfl_down(best, off);
            int   oi = __shfl_down(bi, off);
            if (ov > best || (ov == best && oi < bi)) { best = ov; bi = oi; }
        }
        if (lane == 0) { wvv[wid] = best; wvi[wid] = bi; }
        __syncthreads();
        if (tid == 0) {
            float bb = wvv[0]; int bbi = wvi[0];
#pragma unroll
            for (int k = 1; k < 4; ++k)
                if (wvv[k] > bb || (wvv[k] == bb && wvi[k] < bbi)) { bb = wvv[k]; bbi = wvi[k]; }
            topv[it] = bb; topi[it] = bbi;
            cv[bbi] = -INFINITY;
        }
        __syncthreads();
    }

    if (tid == 0) {
        float mx = topv[0];
        float e[TOPK], s = 0.f;
#pragma unroll
        for (int i = 0; i < TOPK; ++i) { e[i] = expf(topv[i] - mx); s += e[i]; }
        const float inv = 1.0f / s;
#pragma unroll
        for (int i = 0; i < TOPK; ++i) {
            w[bh * TOPK + i] = e[i] * inv;
            delays[bh * TOPK + i] = topi[i];
        }
    }
}

// ---------------------------------------------------------------------------
// K4: mid[b,t,c] = sum_i w[bh,i] * V[b,(t - delay_i) % L, c]
// ---------------------------------------------------------------------------
__global__ __launch_bounds__(256)
void gather_combine(const float* __restrict__ V, const float* __restrict__ w,
                    const int* __restrict__ delays, float* __restrict__ mid) {
    const size_t g = (size_t)blockIdx.x * 256 + threadIdx.x;
    const int c4 = (int)(g & 255);
    const int t  = (int)((g >> 8) & (L_SZ - 1));
    const int b  = (int)(g >> 19);
    const int h  = c4 >> 4;
    const int bh = b * H_SZ + h;
    const size_t colbase = (size_t)b * L_SZ * D_SZ + (size_t)c4 * 4;

    float4 acc = {0.f, 0.f, 0.f, 0.f};
#pragma unroll
    for (int i = 0; i < TOPK; ++i) {
        const float wi = w[bh * TOPK + i];
        const int   di = delays[bh * TOPK + i];
        const int   ts = (t - di) & (L_SZ - 1);
        float4 v4 = *(const float4*)(V + colbase + (size_t)ts * D_SZ);
        acc.x += wi * v4.x; acc.y += wi * v4.y;
        acc.z += wi * v4.z; acc.w += wi * v4.w;
    }
    *(float4*)(mid + (size_t)b * L_SZ * D_SZ + (size_t)t * D_SZ + c4 * 4) = acc;
}

// ---------------------------------------------------------------------------
extern "C" void kernel_launch(void* const* d_in, const int* in_sizes, int n_in,
                              void* d_out, int out_size, void* d_ws, size_t ws_size,
                              hipStream_t stream) {
    const float* queries = (const float*)d_in[0];
    const float* keys    = (const float*)d_in[1];
    const float* values  = (const float*)d_in[2];
    const float* Wq = (const float*)d_in[3];
    const float* bq = (const float*)d_in[4];
    const float* Wk = (const float*)d_in[5];
    const float* bk = (const float*)d_in[6];
    const float* Wv = (const float*)d_in[7];
    const float* bv = (const float*)d_in[8];
    const float* Wo = (const float*)d_in[9];
    const float* bo = (const float*)d_in[10];

    const size_t NE = (size_t)M_SZ * D_SZ;          // 16.78M elements
    const size_t WNE = (size_t)D_SZ * D_SZ;         // 1,048,576
    ushort_t* Qb16 = (ushort_t*)d_ws;               // 33.5 MB
    ushort_t* Kb16 = Qb16 + NE;                     // 33.5 MB
    float* Vb   = (float*)(Kb16 + NE);              // 67.1 MB
    float* corr = Vb + NE;                          // 1 MB (B*H*L fp32)
    float* wbuf = corr + (size_t)B_SZ * H_SZ * L_SZ;
    int*   dbuf = (int*)(wbuf + B_SZ * H_SZ * TOPK);
    ushort_t* WS = (ushort_t*)(dbuf + B_SZ * H_SZ * TOPK);  // W split region
    float* mid  = (float*)d_ws;  // aliases Qb16+Kb16 (67MB, dead after corr)

    dim3 ggemm(D_SZ / 256, M_SZ / 256);   // (4, 64)
    const int wn8 = (int)(WNE / 8);       // 131072

    // batched W-split needs 4 x (hi+lo) = 16 MB at WS; guard on ws_size.
    const size_t ws_off  = (size_t)((char*)WS - (char*)d_ws);
    const bool batched = ws_size >= ws_off + 4 * 2 * WNE * sizeof(ushort_t);

    if (batched) {
        split_fp32_x4<<<dim3(512, 4), 256, 0, stream>>>(Wq, Wk, Wv, Wo, WS);
        gemm256<true><<<ggemm, 512, 0, stream>>>(
            queries, WS + 0 * 2 * WNE, WS + 0 * 2 * WNE + WNE, bq, Qb16);
        gemm256<true><<<ggemm, 512, 0, stream>>>(
            keys,    WS + 1 * 2 * WNE, WS + 1 * 2 * WNE + WNE, bk, Kb16);
        gemm256<false><<<ggemm, 512, 0, stream>>>(
            values,  WS + 2 * 2 * WNE, WS + 2 * 2 * WNE + WNE, bv, Vb);
    } else {
        ushort_t* WH = WS;
        ushort_t* WL = WS + WNE;
        split_fp32<<<(wn8 + 255) / 256, 256, 0, stream>>>(Wq, WH, WL, wn8);
        gemm256<true><<<ggemm, 512, 0, stream>>>(queries, WH, WL, bq, Qb16);
        split_fp32<<<(wn8 + 255) / 256, 256, 0, stream>>>(Wk, WH, WL, wn8);
        gemm256<true><<<ggemm, 512, 0, stream>>>(keys, WH, WL, bk, Kb16);
        split_fp32<<<(wn8 + 255) / 256, 256, 0, stream>>>(Wv, WH, WL, wn8);
        gemm256<false><<<ggemm, 512, 0, stream>>>(values, WH, WL, bv, Vb);
    }

    zero_f32<<<(B_SZ * H_SZ * L_SZ / 4 + 255) / 256, 256, 0, stream>>>(
        corr, B_SZ * H_SZ * L_SZ / 4);

    corr_mfma<<<dim3(B_SZ * H_SZ, 4), 256, 0, stream>>>(Qb16, Kb16, corr);

    topk_softmax<<<B_SZ * H_SZ, 256, 0, stream>>>(corr, wbuf, dbuf);

    gather_combine<<<(M_SZ * 256) / 256, 256, 0, stream>>>(Vb, wbuf, dbuf, mid);

    if (batched) {
        gemm256<false><<<ggemm, 512, 0, stream>>>(
            mid, WS + 3 * 2 * WNE, WS + 3 * 2 * WNE + WNE, bo, (float*)d_out);
    } else {
        ushort_t* WH = WS;
        ushort_t* WL = WS + WNE;
        split_fp32<<<(wn8 + 255) / 256, 256, 0, stream>>>(Wo, WH, WL, wn8);
        gemm256<false><<<ggemm, 512, 0, stream>>>(mid, WH, WL, bo, (float*)d_out);
    }
}